// Round 6
// baseline (290.094 us; speedup 1.0000x reference)
//
#include <hip/hip_runtime.h>

#define B_  4
#define N_  4096
#define C_  256
#define D_  128
#define M_  4095
#define BN_ (B_ * N_)
#define KSPLIT 4
#define KEYS_PER_SPLIT (N_ / KSPLIT)   // 1024
#define KTILES (KEYS_PER_SPLIT / 64)   // 16

typedef _Float16 half_t;
typedef __attribute__((ext_vector_type(8))) _Float16 half8;
typedef __attribute__((ext_vector_type(4))) float f32x4;

#define MFMA16x16x32(A, B, C) __builtin_amdgcn_mfma_f32_16x16x32_f16(A, B, C, 0, 0, 0)

// ---- prep: transpose weights into B-fragment layouts (runs once, tiny) ----
__global__ __launch_bounds__(256) void prep_kernel(
    const float* __restrict__ Wt, const float* __restrict__ Wp,
    const float* __restrict__ Wg, const float* __restrict__ Wf,
    half_t* __restrict__ WT_hi, half_t* __restrict__ WT_lo,
    half_t* __restrict__ WfT)
{
    const int idx = blockIdx.x * 256 + threadIdx.x;   // 0..32767
    const int wsel = blockIdx.y;
    if (wsel < 3) {
        const float* __restrict__ W = (wsel == 0) ? Wt : (wsel == 1) ? Wp : Wg;
        const int d = idx >> 8, c = idx & 255;
        const float v = W[(size_t)c * D_ + d];
        const half_t h = (half_t)v;
        WT_hi[(size_t)wsel * 32768 + idx] = h;
        WT_lo[(size_t)wsel * 32768 + idx] = (half_t)(v - (float)h);
    } else {
        const int c = idx >> 7, d = idx & 127;
        WfT[idx] = (half_t)Wf[(size_t)d * C_ + c];
    }
}

// ---- proj (MFMA, 3-term split ~= fp32): theta/phi/g = x @ W ----
// grid (BN_/128, 3), block 256 (4 waves). LDS = 40,960 B.
__global__ __launch_bounds__(256) void proj_kernel(
    const float* __restrict__ x, const half_t* __restrict__ WT_hi,
    const half_t* __restrict__ WT_lo, float* __restrict__ ws)
{
    const int tid = threadIdx.x;
    const int lane = tid & 63;
    const int w = tid >> 6;
    const int lm = lane & 15;
    const int lq = lane >> 4;
    const int r0 = blockIdx.x * 128;
    const int which = blockIdx.y;
    float* __restrict__ outp = ws + (size_t)which * BN_ * D_;
    const half_t* __restrict__ Wh_g = WT_hi + (size_t)which * 32768;
    const half_t* __restrict__ Wl_g = WT_lo + (size_t)which * 32768;

    __shared__ half_t Xh[128][40], Xl[128][40];
    __shared__ half_t Whl[128][40], Wll[128][40];

    f32x4 acc[2][8];
#pragma unroll
    for (int rb = 0; rb < 2; ++rb)
#pragma unroll
        for (int nb = 0; nb < 8; ++nb)
#pragma unroll
            for (int r = 0; r < 4; ++r) acc[rb][nb][r] = 0.f;

    const int sr = tid >> 1;
    const int cL = (tid & 1) * 16;

    for (int kc = 0; kc < 8; ++kc) {
        __syncthreads();
        {
            const float* xs = x + (size_t)(r0 + sr) * C_ + kc * 32 + cL;
            float vv[16];
            float4 v0 = *(const float4*)&xs[0], v1 = *(const float4*)&xs[4];
            float4 v2 = *(const float4*)&xs[8], v3 = *(const float4*)&xs[12];
            vv[0]=v0.x; vv[1]=v0.y; vv[2]=v0.z; vv[3]=v0.w;
            vv[4]=v1.x; vv[5]=v1.y; vv[6]=v1.z; vv[7]=v1.w;
            vv[8]=v2.x; vv[9]=v2.y; vv[10]=v2.z; vv[11]=v2.w;
            vv[12]=v3.x; vv[13]=v3.y; vv[14]=v3.z; vv[15]=v3.w;
            half8 hi[2], lo[2];
#pragma unroll
            for (int j = 0; j < 16; ++j) {
                half_t h = (half_t)vv[j];
                hi[j >> 3][j & 7] = h;
                lo[j >> 3][j & 7] = (half_t)(vv[j] - (float)h);
            }
            *(half8*)&Xh[sr][cL] = hi[0]; *(half8*)&Xh[sr][cL + 8] = hi[1];
            *(half8*)&Xl[sr][cL] = lo[0]; *(half8*)&Xl[sr][cL + 8] = lo[1];
            const half_t* wh = Wh_g + (size_t)sr * 256 + kc * 32 + cL;
            const half_t* wl = Wl_g + (size_t)sr * 256 + kc * 32 + cL;
            *(half8*)&Whl[sr][cL] = *(const half8*)&wh[0];
            *(half8*)&Whl[sr][cL + 8] = *(const half8*)&wh[8];
            *(half8*)&Wll[sr][cL] = *(const half8*)&wl[0];
            *(half8*)&Wll[sr][cL + 8] = *(const half8*)&wl[8];
        }
        __syncthreads();

        half8 ah[2], al[2];
#pragma unroll
        for (int rb = 0; rb < 2; ++rb) {
            ah[rb] = *(const half8*)&Xh[w * 32 + rb * 16 + lm][lq * 8];
            al[rb] = *(const half8*)&Xl[w * 32 + rb * 16 + lm][lq * 8];
        }
#pragma unroll
        for (int nb = 0; nb < 8; ++nb) {
            half8 bh = *(const half8*)&Whl[nb * 16 + lm][lq * 8];
            half8 bl = *(const half8*)&Wll[nb * 16 + lm][lq * 8];
#pragma unroll
            for (int rb = 0; rb < 2; ++rb) {
                acc[rb][nb] = MFMA16x16x32(ah[rb], bh, acc[rb][nb]);
                acc[rb][nb] = MFMA16x16x32(al[rb], bh, acc[rb][nb]);
                acc[rb][nb] = MFMA16x16x32(ah[rb], bl, acc[rb][nb]);
            }
        }
    }
#pragma unroll
    for (int rb = 0; rb < 2; ++rb)
#pragma unroll
        for (int nb = 0; nb < 8; ++nb)
#pragma unroll
            for (int r = 0; r < 4; ++r)
                outp[(size_t)(r0 + w * 32 + rb * 16 + lq * 4 + r) * D_ +
                     nb * 16 + lm] = acc[rb][nb][r];
}

// ------- pool: maxpool(2,1) -> pphi fp16 [b][m][d], pgT fp16 [b][d][m] -------
__global__ __launch_bounds__(256) void pool_kernel(
    const float* __restrict__ phi, const float* __restrict__ g,
    half_t* __restrict__ pphi, half_t* __restrict__ pgT)
{
    const int tid = threadIdx.x;
    const int t0 = blockIdx.x * 64;
    const int b = blockIdx.y;
    const float* __restrict__ pb = phi + (size_t)b * N_ * D_;
    const float* __restrict__ gb = g + (size_t)b * N_ * D_;

    __shared__ half_t Gs[64][136];

    {
        const int r = tid >> 2;
        const int cc = (tid & 3) * 32;
        const int m0 = t0 + r;
        const int m1 = (m0 + 1 < N_) ? m0 + 1 : m0;
        float pv[32], gv[32];
#pragma unroll
        for (int j = 0; j < 8; ++j) {
            float4 a  = *(const float4*)&pb[(size_t)m0 * D_ + cc + j * 4];
            float4 a2 = *(const float4*)&pb[(size_t)m1 * D_ + cc + j * 4];
            float4 v  = *(const float4*)&gb[(size_t)m0 * D_ + cc + j * 4];
            float4 v2 = *(const float4*)&gb[(size_t)m1 * D_ + cc + j * 4];
            pv[j*4+0] = fmaxf(a.x, a2.x); pv[j*4+1] = fmaxf(a.y, a2.y);
            pv[j*4+2] = fmaxf(a.z, a2.z); pv[j*4+3] = fmaxf(a.w, a2.w);
            gv[j*4+0] = fmaxf(v.x, v2.x); gv[j*4+1] = fmaxf(v.y, v2.y);
            gv[j*4+2] = fmaxf(v.z, v2.z); gv[j*4+3] = fmaxf(v.w, v2.w);
        }
        half8 hp[4];
#pragma unroll
        for (int j = 0; j < 32; ++j) {
            hp[j >> 3][j & 7] = (half_t)pv[j];
            Gs[r][cc + j] = (half_t)gv[j];
        }
        half8* dst = (half8*)&pphi[((size_t)b * N_ + m0) * D_ + cc];
#pragma unroll
        for (int j = 0; j < 4; ++j) dst[j] = hp[j];
    }
    __syncthreads();
    {
        const int d = tid >> 1;
        const int k2 = (tid & 1) * 32;
        half8 hb[4];
#pragma unroll
        for (int j = 0; j < 32; ++j) hb[j >> 3][j & 7] = Gs[k2 + j][d];
        half8* gdst = (half8*)&pgT[(size_t)b * D_ * N_ + (size_t)d * N_ + t0 + k2];
#pragma unroll
        for (int j = 0; j < 4; ++j) gdst[j] = hb[j];
    }
}

// ---------------- MFMA flash attention: barrier-free K-loop ----------------
// K and G B-fragments read DIRECTLY from global (fragment-contiguous layouts);
// only P goes through LDS and it is wave-private -> zero __syncthreads.
// grid (N_/128, KSPLIT, B_) = 512 blocks, 256 thr. LDS = 18,432 B.
__global__ __launch_bounds__(256, 2) void attn_kernel(
    const float* __restrict__ theta, const half_t* __restrict__ pphi,
    const half_t* __restrict__ pgT, half_t* __restrict__ ypart,
    float* __restrict__ mstat, float* __restrict__ lstat)
{
    const int tid = threadIdx.x;
    const int lane = tid & 63;
    const int w = tid >> 6;
    const int lm = lane & 15;
    const int lq = lane >> 4;
    const int qt = blockIdx.x, ks = blockIdx.y, b = blockIdx.z;
    const int q0 = qt * 128;

    __shared__ half_t Ps[128][72];   // P [query][key], wave-private rows

    const half_t* __restrict__ Kb = pphi + (size_t)b * N_ * D_;
    const half_t* __restrict__ Gb = pgT + (size_t)b * D_ * N_;

    // Q fragments: rows q0 + w*32 + rb*16 + lm, split hi/lo
    half8 qhi[2][4], qlo[2][4];
#pragma unroll
    for (int rb = 0; rb < 2; ++rb) {
        const float* tr_ = theta + ((size_t)b * N_ + q0 + w * 32 + rb * 16 + lm) * D_;
#pragma unroll
        for (int c = 0; c < 4; ++c) {
            const float* p = tr_ + c * 32 + lq * 8;
            float4 v0 = *(const float4*)p;
            float4 v1 = *(const float4*)(p + 4);
            float vv[8] = {v0.x, v0.y, v0.z, v0.w, v1.x, v1.y, v1.z, v1.w};
#pragma unroll
            for (int j = 0; j < 8; ++j) {
                half_t h = (half_t)vv[j];
                qhi[rb][c][j] = h;
                qlo[rb][c][j] = (half_t)(vv[j] - (float)h);
            }
        }
    }

    float m_r[2][4], l_r[2][4];
#pragma unroll
    for (int rb = 0; rb < 2; ++rb)
#pragma unroll
        for (int r = 0; r < 4; ++r) { m_r[rb][r] = -1e30f; l_r[rb][r] = 0.f; }
    f32x4 yacc[2][8];
#pragma unroll
    for (int rb = 0; rb < 2; ++rb)
#pragma unroll
        for (int db = 0; db < 8; ++db)
#pragma unroll
            for (int r = 0; r < 4; ++r) yacc[rb][db][r] = 0.f;

    for (int kt = 0; kt < KTILES; ++kt) {
        const int k0 = ks * KEYS_PER_SPLIT + kt * 64;

        // QK^T: kf B-frags straight from global [key][d] (16B contiguous)
        f32x4 sc[2][4];
#pragma unroll
        for (int rb = 0; rb < 2; ++rb)
#pragma unroll
            for (int kb = 0; kb < 4; ++kb)
#pragma unroll
                for (int r = 0; r < 4; ++r) sc[rb][kb][r] = 0.f;
#pragma unroll
        for (int kb = 0; kb < 4; ++kb) {
#pragma unroll
            for (int c = 0; c < 4; ++c) {
                half8 kf = *(const half8*)&Kb[(size_t)(k0 + kb * 16 + lm) * D_ +
                                              c * 32 + lq * 8];
#pragma unroll
                for (int rb = 0; rb < 2; ++rb) {
                    sc[rb][kb] = MFMA16x16x32(qlo[rb][c], kf, sc[rb][kb]);
                    sc[rb][kb] = MFMA16x16x32(qhi[rb][c], kf, sc[rb][kb]);
                }
            }
        }
        // mask padded key 4095
#pragma unroll
        for (int kb = 0; kb < 4; ++kb) {
            if (k0 + kb * 16 + lm >= M_) {
#pragma unroll
                for (int r = 0; r < 4; ++r) { sc[0][kb][r] = -1e30f; sc[1][kb][r] = -1e30f; }
            }
        }
        // online softmax (reduce across 16 key-lanes)
        float alpha[2][4];
#pragma unroll
        for (int rb = 0; rb < 2; ++rb) {
#pragma unroll
            for (int r = 0; r < 4; ++r) {
                float mt = fmaxf(fmaxf(sc[rb][0][r], sc[rb][1][r]),
                                 fmaxf(sc[rb][2][r], sc[rb][3][r]));
#pragma unroll
                for (int off = 1; off < 16; off <<= 1)
                    mt = fmaxf(mt, __shfl_xor(mt, off, 16));
                const float mnew = fmaxf(m_r[rb][r], mt);
                alpha[rb][r] = __expf(m_r[rb][r] - mnew);
                m_r[rb][r] = mnew;
                float rs = 0.f;
#pragma unroll
                for (int kb = 0; kb < 4; ++kb) {
                    float pz = __expf(sc[rb][kb][r] - mnew);
                    sc[rb][kb][r] = pz;
                    rs += pz;
                }
#pragma unroll
                for (int off = 1; off < 16; off <<= 1)
                    rs += __shfl_xor(rs, off, 16);
                l_r[rb][r] = l_r[rb][r] * alpha[rb][r] + rs;
            }
        }
        // stage P through LDS (wave-private rows: program-order suffices)
#pragma unroll
        for (int rb = 0; rb < 2; ++rb)
#pragma unroll
            for (int kb = 0; kb < 4; ++kb)
#pragma unroll
                for (int r = 0; r < 4; ++r)
                    Ps[w * 32 + rb * 16 + lq * 4 + r][kb * 16 + lm] =
                        (half_t)sc[rb][kb][r];
        // rescale accumulator
#pragma unroll
        for (int rb = 0; rb < 2; ++rb)
#pragma unroll
            for (int db = 0; db < 8; ++db)
#pragma unroll
                for (int r = 0; r < 4; ++r) yacc[rb][db][r] *= alpha[rb][r];
        // PV: pf from LDS; gf B-frags straight from global [d][key]
        half8 pf[2][2];
#pragma unroll
        for (int rb = 0; rb < 2; ++rb)
#pragma unroll
            for (int c2 = 0; c2 < 2; ++c2)
                pf[rb][c2] = *(const half8*)&Ps[w * 32 + rb * 16 + lm][c2 * 32 + lq * 8];
#pragma unroll
        for (int db = 0; db < 8; ++db) {
#pragma unroll
            for (int c2 = 0; c2 < 2; ++c2) {
                half8 gf = *(const half8*)&Gb[(size_t)(db * 16 + lm) * N_ +
                                              k0 + c2 * 32 + lq * 8];
                yacc[0][db] = MFMA16x16x32(pf[0][c2], gf, yacc[0][db]);
                yacc[1][db] = MFMA16x16x32(pf[1][c2], gf, yacc[1][db]);
            }
        }
    }

    // epilogue: unnormalized y partial (fp16) + (m,l) stats
    half_t* yp = ypart + ((size_t)ks * BN_ + (size_t)b * N_) * D_;
#pragma unroll
    for (int rb = 0; rb < 2; ++rb)
#pragma unroll
        for (int db = 0; db < 8; ++db)
#pragma unroll
            for (int r = 0; r < 4; ++r)
                yp[(size_t)(q0 + w * 32 + rb * 16 + lq * 4 + r) * D_ + db * 16 + lm] =
                    (half_t)yacc[rb][db][r];
    if (lm == 0) {
#pragma unroll
        for (int rb = 0; rb < 2; ++rb)
#pragma unroll
            for (int r = 0; r < 4; ++r) {
                const int row = q0 + w * 32 + rb * 16 + lq * 4 + r;
                mstat[(size_t)ks * BN_ + (size_t)b * N_ + row] = m_r[rb][r];
                lstat[(size_t)ks * BN_ + (size_t)b * N_ + row] = l_r[rb][r];
            }
    }
}

// ---- final (MFMA): merge 4 partials, z = x + y @ Wf ----
// grid (BN_/128, 2), block 256. LDS = 38,912 B.
__global__ __launch_bounds__(256) void final_kernel(
    const half_t* __restrict__ ypart, const float* __restrict__ mstat,
    const float* __restrict__ lstat, const float* __restrict__ x,
    const half_t* __restrict__ WfT, float* __restrict__ out)
{
    const int tid = threadIdx.x;
    const int lane = tid & 63;
    const int w = tid >> 6;
    const int lm = lane & 15;
    const int lq = lane >> 4;
    const int r0 = blockIdx.x * 128;
    const int c0 = blockIdx.y * 128;

    __shared__ half_t Ys[128][72];
    __shared__ half_t Wfs[128][72];
    __shared__ float scl[4][128];

    if (tid < 128) {
        const int row = r0 + tid;
        float mv[4], lv[4], wv[4];
        float Mx = -1e30f;
#pragma unroll
        for (int s = 0; s < 4; ++s) {
            mv[s] = mstat[(size_t)s * BN_ + row];
            lv[s] = lstat[(size_t)s * BN_ + row];
            Mx = fmaxf(Mx, mv[s]);
        }
        float lsum = 0.f;
#pragma unroll
        for (int s = 0; s < 4; ++s) { wv[s] = __expf(mv[s] - Mx); lsum += wv[s] * lv[s]; }
        const float inv = 1.f / lsum;
#pragma unroll
        for (int s = 0; s < 4; ++s) scl[s][tid] = wv[s] * inv;
    }
    __syncthreads();

    f32x4 acc[2][8];
#pragma unroll
    for (int rb = 0; rb < 2; ++rb)
#pragma unroll
        for (int nb = 0; nb < 8; ++nb)
#pragma unroll
            for (int r = 0; r < 4; ++r) acc[rb][nb][r] = 0.f;

    const int sr = tid >> 1;
    const int dd = (tid & 1) * 32;

    for (int kc = 0; kc < 2; ++kc) {
        {
            const float s0 = scl[0][sr], s1 = scl[1][sr],
                        s2 = scl[2][sr], s3 = scl[3][sr];
            const size_t yb = (size_t)(r0 + sr) * D_ + kc * 64 + dd;
            half8 o[4];
#pragma unroll
            for (int q = 0; q < 4; ++q) {
                half8 y0 = *(const half8*)&ypart[0 * (size_t)BN_ * D_ + yb + q * 8];
                half8 y1 = *(const half8*)&ypart[1 * (size_t)BN_ * D_ + yb + q * 8];
                half8 y2 = *(const half8*)&ypart[2 * (size_t)BN_ * D_ + yb + q * 8];
                half8 y3 = *(const half8*)&ypart[3 * (size_t)BN_ * D_ + yb + q * 8];
#pragma unroll
                for (int j = 0; j < 8; ++j)
                    o[q][j] = (half_t)(s0 * (float)y0[j] + s1 * (float)y1[j] +
                                       s2 * (float)y2[j] + s3 * (float)y3[j]);
            }
#pragma unroll
            for (int q = 0; q < 4; ++q) *(half8*)&Ys[sr][dd + q * 8] = o[q];
            const half_t* wf = WfT + (size_t)(c0 + sr) * D_ + kc * 64 + dd;
#pragma unroll
            for (int q = 0; q < 4; ++q)
                *(half8*)&Wfs[sr][dd + q * 8] = *(const half8*)&wf[q * 8];
        }
        __syncthreads();

        half8 af[2][2];
#pragma unroll
        for (int rb = 0; rb < 2; ++rb)
#pragma unroll
            for (int k2 = 0; k2 < 2; ++k2)
                af[rb][k2] = *(const half8*)&Ys[w * 32 + rb * 16 + lm][k2 * 32 + lq * 8];
#pragma unroll
        for (int nb = 0; nb < 8; ++nb) {
#pragma unroll
            for (int k2 = 0; k2 < 2; ++k2) {
                half8 bf = *(const half8*)&Wfs[nb * 16 + lm][k2 * 32 + lq * 8];
                acc[0][nb] = MFMA16x16x32(af[0][k2], bf, acc[0][nb]);
                acc[1][nb] = MFMA16x16x32(af[1][k2], bf, acc[1][nb]);
            }
        }
        __syncthreads();
    }
#pragma unroll
    for (int rb = 0; rb < 2; ++rb)
#pragma unroll
        for (int nb = 0; nb < 8; ++nb)
#pragma unroll
            for (int r = 0; r < 4; ++r) {
                const int row = r0 + w * 32 + rb * 16 + lq * 4 + r;
                const int col = c0 + nb * 16 + lm;
                out[(size_t)row * C_ + col] =
                    acc[rb][nb][r] + x[(size_t)row * C_ + col];
            }
}

extern "C" void kernel_launch(void* const* d_in, const int* in_sizes, int n_in,
                              void* d_out, int out_size, void* d_ws, size_t ws_size,
                              hipStream_t stream)
{
    const float* x  = (const float*)d_in[0];
    const float* Wt = (const float*)d_in[1];
    const float* Wp = (const float*)d_in[2];
    const float* Wg = (const float*)d_in[3];
    const float* Wf = (const float*)d_in[4];
    float* out = (float*)d_out;

    const size_t SEG = (size_t)BN_ * D_;
    float* ws    = (float*)d_ws;
    float* theta = ws;
    float* phi_r = ws + 1 * SEG;
    float* g_r   = ws + 2 * SEG;
    half_t* pphi = (half_t*)(ws + 3 * SEG);
    half_t* pgT  = (half_t*)(ws + 3 * SEG + SEG / 2);
    float* seg4  = ws + 4 * SEG;
    float* mstat = seg4;
    float* lstat = seg4 + (size_t)KSPLIT * BN_;
    half_t* WT_hi = (half_t*)(seg4 + 2 * (size_t)KSPLIT * BN_);
    half_t* WT_lo = WT_hi + 3 * 32768;
    half_t* WfT   = WT_lo + 3 * 32768;
    half_t* ypart = (half_t*)(ws + 1 * SEG);

    prep_kernel<<<dim3(128, 4), 256, 0, stream>>>(Wt, Wp, Wg, Wf, WT_hi, WT_lo, WfT);
    proj_kernel<<<dim3(BN_ / 128, 3), 256, 0, stream>>>(x, WT_hi, WT_lo, ws);
    pool_kernel<<<dim3(N_ / 64, B_), 256, 0, stream>>>(phi_r, g_r, pphi, pgT);
    attn_kernel<<<dim3(N_ / 128, KSPLIT, B_), 256, 0, stream>>>(
        theta, pphi, pgT, ypart, mstat, lstat);
    final_kernel<<<dim3(BN_ / 128, 2), 256, 0, stream>>>(
        ypart, mstat, lstat, x, WfT, out);
}

// Round 8
// 184.619 us; speedup vs baseline: 1.5713x; 1.5713x over previous
//
#include <hip/hip_runtime.h>

#define B_  4
#define N_  4096
#define C_  256
#define D_  128
#define M_  4095
#define BN_ (B_ * N_)
#define KSPLIT 4
#define KEYS_PER_SPLIT (N_ / KSPLIT)   // 1024
#define KTILES (KEYS_PER_SPLIT / 64)   // 16

typedef _Float16 half_t;
typedef __attribute__((ext_vector_type(8))) _Float16 half8;
typedef __attribute__((ext_vector_type(4))) _Float16 half4;
typedef __attribute__((ext_vector_type(4))) float f32x4;

#define MFMA16x16x32(A, B, C) __builtin_amdgcn_mfma_f32_16x16x32_f16(A, B, C, 0, 0, 0)

// ---- prep: weights into B-fragment layouts (runs once, tiny) ----
__global__ __launch_bounds__(256) void prep_kernel(
    const float* __restrict__ Wt, const float* __restrict__ Wp,
    const float* __restrict__ Wg, const float* __restrict__ Wf,
    half_t* __restrict__ WT_hi, half_t* __restrict__ WT_lo,
    half_t* __restrict__ WfT)
{
    const int idx = blockIdx.x * 256 + threadIdx.x;   // 0..32767
    const int wsel = blockIdx.y;
    if (wsel < 3) {
        const float* __restrict__ W = (wsel == 0) ? Wt : (wsel == 1) ? Wp : Wg;
        const int d = idx >> 8, c = idx & 255;
        const float v = W[(size_t)c * D_ + d];
        const half_t h = (half_t)v;
        WT_hi[(size_t)wsel * 32768 + idx] = h;
        WT_lo[(size_t)wsel * 32768 + idx] = (half_t)(v - (float)h);
    } else {
        const int c = idx >> 7, d = idx & 127;
        WfT[idx] = (half_t)Wf[(size_t)d * C_ + c];
    }
}

// ---- proj (MFMA, 3-term split ~= fp32) + FUSED maxpool/transpose ----
// grid (BN_/128, 3), block 256. which: 0=theta(fp32 out), 1=phi->pphi[m][d] f16,
// 2=g->pgT[d][m] f16. LDS = 40,960 B (staging; reused for pool/transpose).
__global__ __launch_bounds__(256) void proj_kernel(
    const float* __restrict__ x, const half_t* __restrict__ WT_hi,
    const half_t* __restrict__ WT_lo, float* __restrict__ theta,
    half_t* __restrict__ pphi, half_t* __restrict__ pgT)
{
    const int tid = threadIdx.x;
    const int lane = tid & 63;
    const int w = tid >> 6;
    const int lm = lane & 15;
    const int lq = lane >> 4;
    const int r0 = blockIdx.x * 128;
    const int which = blockIdx.y;
    const half_t* __restrict__ Wh_g = WT_hi + (size_t)which * 32768;
    const half_t* __restrict__ Wl_g = WT_lo + (size_t)which * 32768;

    __shared__ __align__(16) unsigned char lds_raw[40960];
    half_t (*Xh)[40]  = (half_t (*)[40])(lds_raw);
    half_t (*Xl)[40]  = (half_t (*)[40])(lds_raw + 10240);
    half_t (*Whl)[40] = (half_t (*)[40])(lds_raw + 20480);
    half_t (*Wll)[40] = (half_t (*)[40])(lds_raw + 30720);

    f32x4 acc[2][8];
#pragma unroll
    for (int rb = 0; rb < 2; ++rb)
#pragma unroll
        for (int nb = 0; nb < 8; ++nb)
#pragma unroll
            for (int r = 0; r < 4; ++r) acc[rb][nb][r] = 0.f;

    const int sr = tid >> 1;
    const int cL = (tid & 1) * 16;

    for (int kc = 0; kc < 8; ++kc) {
        __syncthreads();
        {
            const float* xs = x + (size_t)(r0 + sr) * C_ + kc * 32 + cL;
            float vv[16];
            float4 v0 = *(const float4*)&xs[0], v1 = *(const float4*)&xs[4];
            float4 v2 = *(const float4*)&xs[8], v3 = *(const float4*)&xs[12];
            vv[0]=v0.x; vv[1]=v0.y; vv[2]=v0.z; vv[3]=v0.w;
            vv[4]=v1.x; vv[5]=v1.y; vv[6]=v1.z; vv[7]=v1.w;
            vv[8]=v2.x; vv[9]=v2.y; vv[10]=v2.z; vv[11]=v2.w;
            vv[12]=v3.x; vv[13]=v3.y; vv[14]=v3.z; vv[15]=v3.w;
            half8 hi[2], lo[2];
#pragma unroll
            for (int j = 0; j < 16; ++j) {
                half_t h = (half_t)vv[j];
                hi[j >> 3][j & 7] = h;
                lo[j >> 3][j & 7] = (half_t)(vv[j] - (float)h);
            }
            *(half8*)&Xh[sr][cL] = hi[0]; *(half8*)&Xh[sr][cL + 8] = hi[1];
            *(half8*)&Xl[sr][cL] = lo[0]; *(half8*)&Xl[sr][cL + 8] = lo[1];
            const half_t* wh = Wh_g + (size_t)sr * 256 + kc * 32 + cL;
            const half_t* wl = Wl_g + (size_t)sr * 256 + kc * 32 + cL;
            *(half8*)&Whl[sr][cL] = *(const half8*)&wh[0];
            *(half8*)&Whl[sr][cL + 8] = *(const half8*)&wh[8];
            *(half8*)&Wll[sr][cL] = *(const half8*)&wl[0];
            *(half8*)&Wll[sr][cL + 8] = *(const half8*)&wl[8];
        }
        __syncthreads();

        half8 ah[2], al[2];
#pragma unroll
        for (int rb = 0; rb < 2; ++rb) {
            ah[rb] = *(const half8*)&Xh[w * 32 + rb * 16 + lm][lq * 8];
            al[rb] = *(const half8*)&Xl[w * 32 + rb * 16 + lm][lq * 8];
        }
#pragma unroll
        for (int nb = 0; nb < 8; ++nb) {
            half8 bh = *(const half8*)&Whl[nb * 16 + lm][lq * 8];
            half8 bl = *(const half8*)&Wll[nb * 16 + lm][lq * 8];
#pragma unroll
            for (int rb = 0; rb < 2; ++rb) {
                acc[rb][nb] = MFMA16x16x32(ah[rb], bh, acc[rb][nb]);
                acc[rb][nb] = MFMA16x16x32(al[rb], bh, acc[rb][nb]);
                acc[rb][nb] = MFMA16x16x32(ah[rb], bl, acc[rb][nb]);
            }
        }
    }

    if (which == 0) {   // theta: fp32 direct store
#pragma unroll
        for (int rb = 0; rb < 2; ++rb)
#pragma unroll
            for (int nb = 0; nb < 8; ++nb)
#pragma unroll
                for (int r = 0; r < 4; ++r)
                    theta[(size_t)(r0 + w * 32 + rb * 16 + lq * 4 + r) * D_ +
                          nb * 16 + lm] = acc[rb][nb][r];
        return;
    }

    // ---- fused pool path: acc -> LsT[d][m] fp16, halo row, pool, store ----
    __syncthreads();   // staging arrays dead
    half_t (*LsT)[136] = (half_t (*)[136])(lds_raw);   // 128 x 136 = 34,816 B
#pragma unroll
    for (int rb = 0; rb < 2; ++rb)
#pragma unroll
        for (int nb = 0; nb < 8; ++nb) {
            const int d = nb * 16 + lm;
            const int m = w * 32 + rb * 16 + lq * 4;
            half4 pk;
#pragma unroll
            for (int r = 0; r < 4; ++r) pk[r] = (half_t)acc[rb][nb][r];
            *(half4*)&LsT[d][m] = pk;
        }
    // halo: projected row r0+128 (or r0+127 at batch boundary) -> LsT[d][128]
    if (tid < 128) {
        int rh = r0 + 128;
        if ((rh & (N_ - 1)) == 0) rh = r0 + 127;
        const float* xr = x + (size_t)rh * C_;
        const half_t* wh = Wh_g + (size_t)tid * 256;
        const half_t* wl = Wl_g + (size_t)tid * 256;
        float s = 0.f;
#pragma unroll
        for (int c8 = 0; c8 < 32; ++c8) {
            half8 h = *(const half8*)&wh[c8 * 8];
            half8 l = *(const half8*)&wl[c8 * 8];
            float4 xa = *(const float4*)&xr[c8 * 8];
            float4 xb = *(const float4*)&xr[c8 * 8 + 4];
            s += xa.x * ((float)h[0] + (float)l[0]) + xa.y * ((float)h[1] + (float)l[1])
               + xa.z * ((float)h[2] + (float)l[2]) + xa.w * ((float)h[3] + (float)l[3])
               + xb.x * ((float)h[4] + (float)l[4]) + xb.y * ((float)h[5] + (float)l[5])
               + xb.z * ((float)h[6] + (float)l[6]) + xb.w * ((float)h[7] + (float)l[7]);
        }
        LsT[tid][128] = (half_t)s;
    }
    __syncthreads();

    if (which == 1) {   // pooled phi -> pphi[m][d]
        const int m = tid >> 1, dh = (tid & 1) * 64;
        half8 o[8];
#pragma unroll
        for (int j = 0; j < 64; ++j) {
            float v0 = (float)LsT[dh + j][m];
            float v1 = (float)LsT[dh + j][m + 1];
            o[j >> 3][j & 7] = (half_t)fmaxf(v0, v1);
        }
        half8* dst = (half8*)&pphi[(size_t)(r0 + m) * D_ + dh];
#pragma unroll
        for (int j = 0; j < 8; ++j) dst[j] = o[j];
    } else {            // pooled g -> pgT[b][d][m]
        const int d = tid >> 1, mh = (tid & 1) * 64;
        const int b = r0 / N_, m0 = r0 & (N_ - 1);
        half8 in[8];
#pragma unroll
        for (int j = 0; j < 8; ++j) in[j] = *(const half8*)&LsT[d][mh + j * 8];
        const half_t ext = LsT[d][mh + 64];
        half8 o[8];
#pragma unroll
        for (int j = 0; j < 64; ++j) {
            float v0 = (float)in[j >> 3][j & 7];
            float v1 = (j == 63) ? (float)ext : (float)in[(j + 1) >> 3][(j + 1) & 7];
            o[j >> 3][j & 7] = (half_t)fmaxf(v0, v1);
        }
        half8* dst = (half8*)&pgT[((size_t)b * D_ + d) * N_ + m0 + mh];
#pragma unroll
        for (int j = 0; j < 8; ++j) dst[j] = o[j];
    }
}

// ---------------- MFMA flash attention, transposed scores ----------------
// S^T = K.Q^T (lane = q, keys in regs): in-lane softmax, b64 P stores.
// alpha must be lane-transposed (q=lm -> q=lq*4+r) before rescaling yacc.
// grid (N_/128, KSPLIT, B_) = 512 blocks, 256 thr. LDS = 54,272 B.
__global__ __launch_bounds__(256, 2) void attn_kernel(
    const float* __restrict__ theta, const half_t* __restrict__ pphi,
    const half_t* __restrict__ pgT, half_t* __restrict__ ypart,
    float* __restrict__ mstat, float* __restrict__ lstat)
{
    const int tid = threadIdx.x;
    const int lane = tid & 63;
    const int w = tid >> 6;
    const int lm = lane & 15;
    const int lq = lane >> 4;      // 0..3
    const int qt = blockIdx.x, ksb = blockIdx.y, b = blockIdx.z;
    const int q0 = qt * 128;

    __shared__ half_t Ks[64][136];   // K tile [key][d]        17,408 B
    __shared__ half_t Gts[128][72];  // G tile [d][key]        18,432 B
    __shared__ half_t Ps[128][72];   // P [q][key] wave-private 18,432 B

    // Q B-frags (B[k=d][n=q]): lane n=lm -> per-lane theta row, hi/lo split
    half8 qh[2][4], ql[2][4];
#pragma unroll
    for (int nb = 0; nb < 2; ++nb) {
        const float* tr_ = theta + ((size_t)b * N_ + q0 + w * 32 + nb * 16 + lm) * D_;
#pragma unroll
        for (int k4 = 0; k4 < 4; ++k4) {
            const float* p = tr_ + k4 * 32 + lq * 8;
            float4 v0 = *(const float4*)p;
            float4 v1 = *(const float4*)(p + 4);
            float vv[8] = {v0.x, v0.y, v0.z, v0.w, v1.x, v1.y, v1.z, v1.w};
#pragma unroll
            for (int j = 0; j < 8; ++j) {
                half_t h = (half_t)vv[j];
                qh[nb][k4][j] = h;
                ql[nb][k4][j] = (half_t)(vv[j] - (float)h);
            }
        }
    }

    float m_i[2] = {-1e30f, -1e30f};
    float l_i[2] = {0.f, 0.f};
    f32x4 yacc[2][8];
#pragma unroll
    for (int mb = 0; mb < 2; ++mb)
#pragma unroll
        for (int dn = 0; dn < 8; ++dn)
#pragma unroll
            for (int r = 0; r < 4; ++r) yacc[mb][dn][r] = 0.f;

    for (int kt = 0; kt < KTILES; ++kt) {
        const int k0 = ksb * KEYS_PER_SPLIT + kt * 64;
        __syncthreads();
        {   // stage K [key][d] and G^T [d][key] cooperatively (coalesced)
            const int key = tid >> 2, ch = (tid & 3);
            const float4* src = (const float4*)(pphi +
                ((size_t)b * N_ + k0 + key) * D_ + ch * 32);
            float4 a0 = src[0], a1 = src[1], a2 = src[2], a3 = src[3];
            float4* dst = (float4*)&Ks[key][ch * 32];
            dst[0] = a0; dst[1] = a1; dst[2] = a2; dst[3] = a3;
            const int d = tid >> 1, kh = (tid & 1);
            const float4* gs = (const float4*)(pgT +
                ((size_t)b * D_ + d) * N_ + k0 + kh * 32);
            float4 g0 = gs[0], g1 = gs[1], g2 = gs[2], g3 = gs[3];
            float4* gd = (float4*)&Gts[d][kh * 32];
            gd[0] = g0; gd[1] = g1; gd[2] = g2; gd[3] = g3;
        }
        __syncthreads();

        // QK^T transposed: S^T[key][q]; A = K (LDS), B = Q (regs)
        f32x4 sc[4][2];
#pragma unroll
        for (int kb = 0; kb < 4; ++kb)
#pragma unroll
            for (int nb = 0; nb < 2; ++nb)
#pragma unroll
                for (int r = 0; r < 4; ++r) sc[kb][nb][r] = 0.f;
#pragma unroll
        for (int kb = 0; kb < 4; ++kb) {
#pragma unroll
            for (int k4 = 0; k4 < 4; ++k4) {
                half8 kf = *(const half8*)&Ks[kb * 16 + lm][k4 * 32 + lq * 8];
#pragma unroll
                for (int nb = 0; nb < 2; ++nb) {
                    sc[kb][nb] = MFMA16x16x32(kf, ql[nb][k4], sc[kb][nb]);
                    sc[kb][nb] = MFMA16x16x32(kf, qh[nb][k4], sc[kb][nb]);
                }
            }
        }
        // mask padded key 4095 (only last tile of last split)
        if (k0 + 64 > M_) {
#pragma unroll
            for (int kb = 0; kb < 4; ++kb)
#pragma unroll
                for (int r = 0; r < 4; ++r)
                    if (k0 + kb * 16 + lq * 4 + r >= M_) {
                        sc[kb][0][r] = -1e30f; sc[kb][1][r] = -1e30f;
                    }
        }
        // online softmax: keys in-lane (16) + across lq quads (2 shuffles);
        // resulting m/l/alpha live per-lane at q = lm.
        float alpha[2];
#pragma unroll
        for (int nb = 0; nb < 2; ++nb) {
            float mt = -1e30f;
#pragma unroll
            for (int kb = 0; kb < 4; ++kb)
#pragma unroll
                for (int r = 0; r < 4; ++r) mt = fmaxf(mt, sc[kb][nb][r]);
            mt = fmaxf(mt, __shfl_xor(mt, 16, 64));
            mt = fmaxf(mt, __shfl_xor(mt, 32, 64));
            const float mnew = fmaxf(m_i[nb], mt);
            alpha[nb] = __expf(m_i[nb] - mnew);
            m_i[nb] = mnew;
            float rs = 0.f;
#pragma unroll
            for (int kb = 0; kb < 4; ++kb)
#pragma unroll
                for (int r = 0; r < 4; ++r) {
                    float p = __expf(sc[kb][nb][r] - mnew);
                    sc[kb][nb][r] = p;
                    rs += p;
                }
            rs += __shfl_xor(rs, 16, 64);
            rs += __shfl_xor(rs, 32, 64);
            l_i[nb] = l_i[nb] * alpha[nb] + rs;
            // P store: 4 consecutive keys at fixed q -> one b64 per (kb)
#pragma unroll
            for (int kb = 0; kb < 4; ++kb) {
                half4 pk;
#pragma unroll
                for (int r = 0; r < 4; ++r) pk[r] = (half_t)sc[kb][nb][r];
                *(half4*)&Ps[w * 32 + nb * 16 + lm][kb * 16 + lq * 4] = pk;
            }
        }
        // FIX (r7 bug): transpose alpha from (q=lm) lane layout to the
        // accumulator's (q=lq*4+r) layout. alpha is uniform across quads for
        // fixed lm, so width-16 shuffle from lane lm'=lq*4+r is exact.
        float alpha_t[2][4];
#pragma unroll
        for (int mb = 0; mb < 2; ++mb)
#pragma unroll
            for (int r = 0; r < 4; ++r)
                alpha_t[mb][r] = __shfl(alpha[mb], lq * 4 + r, 16);
        // rescale accumulator
#pragma unroll
        for (int mb = 0; mb < 2; ++mb)
#pragma unroll
            for (int dn = 0; dn < 8; ++dn)
#pragma unroll
                for (int r = 0; r < 4; ++r) yacc[mb][dn][r] *= alpha_t[mb][r];
        // PV: A = P (LDS, wave-private -> no barrier), B = G^T (LDS)
        half8 pf[2][2];
#pragma unroll
        for (int mb = 0; mb < 2; ++mb)
#pragma unroll
            for (int k2 = 0; k2 < 2; ++k2)
                pf[mb][k2] = *(const half8*)&Ps[w * 32 + mb * 16 + lm][k2 * 32 + lq * 8];
#pragma unroll
        for (int dn = 0; dn < 8; ++dn) {
#pragma unroll
            for (int k2 = 0; k2 < 2; ++k2) {
                half8 gf = *(const half8*)&Gts[dn * 16 + lm][k2 * 32 + lq * 8];
                yacc[0][dn] = MFMA16x16x32(pf[0][k2], gf, yacc[0][dn]);
                yacc[1][dn] = MFMA16x16x32(pf[1][k2], gf, yacc[1][dn]);
            }
        }
    }

    // epilogue: unnormalized y partial (fp16) + (m,l) stats
    half_t* yp = ypart + ((size_t)ksb * BN_ + (size_t)b * N_) * D_;
#pragma unroll
    for (int mb = 0; mb < 2; ++mb)
#pragma unroll
        for (int dn = 0; dn < 8; ++dn)
#pragma unroll
            for (int r = 0; r < 4; ++r)
                yp[(size_t)(q0 + w * 32 + mb * 16 + lq * 4 + r) * D_ + dn * 16 + lm] =
                    (half_t)yacc[mb][dn][r];
    if (lq == 0) {
#pragma unroll
        for (int nb = 0; nb < 2; ++nb) {
            const int row = q0 + w * 32 + nb * 16 + lm;
            mstat[(size_t)ksb * BN_ + (size_t)b * N_ + row] = m_i[nb];
            lstat[(size_t)ksb * BN_ + (size_t)b * N_ + row] = l_i[nb];
        }
    }
}

// ---- final (MFMA): merge 4 partials, z = x + y @ Wf ----
// grid (BN_/128, 2), block 256. LDS = 38,912 B.
__global__ __launch_bounds__(256) void final_kernel(
    const half_t* __restrict__ ypart, const float* __restrict__ mstat,
    const float* __restrict__ lstat, const float* __restrict__ x,
    const half_t* __restrict__ WfT, float* __restrict__ out)
{
    const int tid = threadIdx.x;
    const int lane = tid & 63;
    const int w = tid >> 6;
    const int lm = lane & 15;
    const int lq = lane >> 4;
    const int r0 = blockIdx.x * 128;
    const int c0 = blockIdx.y * 128;

    __shared__ half_t Ys[128][72];
    __shared__ half_t Wfs[128][72];
    __shared__ float scl[4][128];

    if (tid < 128) {
        const int row = r0 + tid;
        float mv[4], lv[4], wv[4];
        float Mx = -1e30f;
#pragma unroll
        for (int s = 0; s < 4; ++s) {
            mv[s] = mstat[(size_t)s * BN_ + row];
            lv[s] = lstat[(size_t)s * BN_ + row];
            Mx = fmaxf(Mx, mv[s]);
        }
        float lsum = 0.f;
#pragma unroll
        for (int s = 0; s < 4; ++s) { wv[s] = __expf(mv[s] - Mx); lsum += wv[s] * lv[s]; }
        const float inv = 1.f / lsum;
#pragma unroll
        for (int s = 0; s < 4; ++s) scl[s][tid] = wv[s] * inv;
    }
    __syncthreads();

    f32x4 acc[2][8];
#pragma unroll
    for (int rb = 0; rb < 2; ++rb)
#pragma unroll
        for (int nb = 0; nb < 8; ++nb)
#pragma unroll
            for (int r = 0; r < 4; ++r) acc[rb][nb][r] = 0.f;

    const int sr = tid >> 1;
    const int dd = (tid & 1) * 32;

    for (int kc = 0; kc < 2; ++kc) {
        {
            const float s0 = scl[0][sr], s1 = scl[1][sr],
                        s2 = scl[2][sr], s3 = scl[3][sr];
            const size_t yb = (size_t)(r0 + sr) * D_ + kc * 64 + dd;
            half8 o[4];
#pragma unroll
            for (int q = 0; q < 4; ++q) {
                half8 y0 = *(const half8*)&ypart[0 * (size_t)BN_ * D_ + yb + q * 8];
                half8 y1 = *(const half8*)&ypart[1 * (size_t)BN_ * D_ + yb + q * 8];
                half8 y2 = *(const half8*)&ypart[2 * (size_t)BN_ * D_ + yb + q * 8];
                half8 y3 = *(const half8*)&ypart[3 * (size_t)BN_ * D_ + yb + q * 8];
#pragma unroll
                for (int j = 0; j < 8; ++j)
                    o[q][j] = (half_t)(s0 * (float)y0[j] + s1 * (float)y1[j] +
                                       s2 * (float)y2[j] + s3 * (float)y3[j]);
            }
#pragma unroll
            for (int q = 0; q < 4; ++q) *(half8*)&Ys[sr][dd + q * 8] = o[q];
            const half_t* wf = WfT + (size_t)(c0 + sr) * D_ + kc * 64 + dd;
#pragma unroll
            for (int q = 0; q < 4; ++q)
                *(half8*)&Wfs[sr][dd + q * 8] = *(const half8*)&wf[q * 8];
        }
        __syncthreads();

        half8 af[2][2];
#pragma unroll
        for (int rb = 0; rb < 2; ++rb)
#pragma unroll
            for (int k2 = 0; k2 < 2; ++k2)
                af[rb][k2] = *(const half8*)&Ys[w * 32 + rb * 16 + lm][k2 * 32 + lq * 8];
#pragma unroll
        for (int nb = 0; nb < 8; ++nb) {
#pragma unroll
            for (int k2 = 0; k2 < 2; ++k2) {
                half8 bf = *(const half8*)&Wfs[nb * 16 + lm][k2 * 32 + lq * 8];
                acc[0][nb] = MFMA16x16x32(af[0][k2], bf, acc[0][nb]);
                acc[1][nb] = MFMA16x16x32(af[1][k2], bf, acc[1][nb]);
            }
        }
        __syncthreads();
    }
#pragma unroll
    for (int rb = 0; rb < 2; ++rb)
#pragma unroll
        for (int nb = 0; nb < 8; ++nb)
#pragma unroll
            for (int r = 0; r < 4; ++r) {
                const int row = r0 + w * 32 + rb * 16 + lq * 4 + r;
                const int col = c0 + nb * 16 + lm;
                out[(size_t)row * C_ + col] =
                    acc[rb][nb][r] + x[(size_t)row * C_ + col];
            }
}

extern "C" void kernel_launch(void* const* d_in, const int* in_sizes, int n_in,
                              void* d_out, int out_size, void* d_ws, size_t ws_size,
                              hipStream_t stream)
{
    const float* x  = (const float*)d_in[0];
    const float* Wt = (const float*)d_in[1];
    const float* Wp = (const float*)d_in[2];
    const float* Wg = (const float*)d_in[3];
    const float* Wf = (const float*)d_in[4];
    float* out = (float*)d_out;

    // ws (fp32 words, SEG = BN_*D_):
    //   [0,1) theta fp32 | [1,1.5) pphi f16 | [1.5,2) pgT f16
    //   [2,4) ypart f16 (4 splits) | then mstat | lstat | WT_hi | WT_lo | WfT
    const size_t SEG = (size_t)BN_ * D_;   // 2,097,152
    float* ws     = (float*)d_ws;
    float* theta  = ws;
    half_t* pphi  = (half_t*)(ws + SEG);
    half_t* pgT   = (half_t*)(ws + SEG + SEG / 2);
    half_t* ypart = (half_t*)(ws + 2 * SEG);
    float* mstat  = ws + 4 * SEG;
    float* lstat  = mstat + (size_t)KSPLIT * BN_;
    half_t* WT_hi = (half_t*)(lstat + (size_t)KSPLIT * BN_);
    half_t* WT_lo = WT_hi + 3 * 32768;
    half_t* WfT   = WT_lo + 3 * 32768;

    prep_kernel<<<dim3(128, 4), 256, 0, stream>>>(Wt, Wp, Wg, Wf, WT_hi, WT_lo, WfT);
    proj_kernel<<<dim3(BN_ / 128, 3), 256, 0, stream>>>(x, WT_hi, WT_lo,
                                                        theta, pphi, pgT);
    attn_kernel<<<dim3(N_ / 128, KSPLIT, B_), 256, 0, stream>>>(
        theta, pphi, pgT, ypart, mstat, lstat);
    final_kernel<<<dim3(BN_ / 128, 2), 256, 0, stream>>>(
        ypart, mstat, lstat, x, WfT, out);
}